// Round 4
// baseline (407.898 us; speedup 1.0000x reference)
//
#include <hip/hip_runtime.h>

// ParallelSelfAttention: S=2048 B=1 H=2048 NH=16 HD=128. I/O = float32 (per reference),
// internal compute = bf16 MFMA with fp32 accumulate.
// QKV GEMM(+bias) -> RoPE(q,k in place) -> V transpose -> flash attn -> dense GEMM.
// Causal triu(k=1) mask with -10000 fill: exp(-10000-m)==0 in fp32 -> exact hard mask.

#define S_LEN 2048
#define NHEAD 16
#define HDIM  128
#define HID   2048
#define H3    6144

typedef short bf16x8 __attribute__((ext_vector_type(8)));
typedef float f32x4  __attribute__((ext_vector_type(4)));

__device__ __forceinline__ float bf2f(ushort u) {
  union { float f; unsigned int i; } v; v.i = ((unsigned int)u) << 16; return v.f;
}
__device__ __forceinline__ ushort f2bf(float f) {
  union { float f; unsigned int i; } v; v.f = f;
  unsigned int r = v.i + 0x7fffu + ((v.i >> 16) & 1u);
  return (ushort)(r >> 16);
}
// 8 consecutive f32 -> 8 bf16 packed in an int4
__device__ __forceinline__ int4 cvt8(const float* p) {
  float4 a = *(const float4*)p, b = *(const float4*)(p + 4);
  union { ushort u[8]; int4 v; } r;
  r.u[0] = f2bf(a.x); r.u[1] = f2bf(a.y); r.u[2] = f2bf(a.z); r.u[3] = f2bf(a.w);
  r.u[4] = f2bf(b.x); r.u[5] = f2bf(b.y); r.u[6] = f2bf(b.z); r.u[7] = f2bf(b.w);
  return r.v;
}

// ---- GEMM: C[M,N] = A @ W^T (+bias). A: f32 (A_F32) or bf16. W: f32 (converted in staging).
// A element (row,k) at A[row*AS + (k>>7)*AH + (k&127)]  (AS=K, AH=128 -> plain row-major).
// C: f32 (OUT_F32) or bf16. 128x128 tile, BK=32, 256 threads.
template<bool A_F32, bool HAS_BIAS, bool OUT_F32>
__global__ __launch_bounds__(256) void gemm_bt(const void* __restrict__ Av,
                                               const float* __restrict__ W,
                                               const float* __restrict__ bias,
                                               void* __restrict__ Cv,
                                               int M, int N, int K, int AS, int AH) {
  __shared__ __align__(16) ushort As[128 * 40];   // +8 pad: rows 16B-aligned, 2-way banks
  __shared__ __align__(16) ushort Ws[128 * 40];
  const int tid  = threadIdx.x;
  const int lane = tid & 63;
  const int w    = tid >> 6;
  const int wr   = w >> 1, wc = w & 1;
  const int quad = lane >> 4, ln15 = lane & 15;
  const int tm = blockIdx.y * 128, tn = blockIdx.x * 128;

  f32x4 acc[4][4];
#pragma unroll
  for (int i = 0; i < 4; ++i)
#pragma unroll
    for (int j = 0; j < 4; ++j) acc[i][j] = (f32x4){0.f, 0.f, 0.f, 0.f};

  const int row0 = tid >> 2, row1 = row0 + 64;
  const int kp   = (tid & 3) * 8;

  for (int k0 = 0; k0 < K; k0 += 32) {
    const int ka   = k0 + kp;
    const int aoff = (ka >> 7) * AH + (ka & 127);
    if (A_F32) {
      const float* A = (const float*)Av;
      *(int4*)&As[row0 * 40 + kp] = cvt8(&A[(size_t)(tm + row0) * AS + aoff]);
      *(int4*)&As[row1 * 40 + kp] = cvt8(&A[(size_t)(tm + row1) * AS + aoff]);
    } else {
      const ushort* A = (const ushort*)Av;
      *(int4*)&As[row0 * 40 + kp] = *(const int4*)&A[(size_t)(tm + row0) * AS + aoff];
      *(int4*)&As[row1 * 40 + kp] = *(const int4*)&A[(size_t)(tm + row1) * AS + aoff];
    }
    *(int4*)&Ws[row0 * 40 + kp] = cvt8(&W[(size_t)(tn + row0) * K + ka]);
    *(int4*)&Ws[row1 * 40 + kp] = cvt8(&W[(size_t)(tn + row1) * K + ka]);
    __syncthreads();
    bf16x8 af[4], bw[4];
#pragma unroll
    for (int i = 0; i < 4; ++i)
      af[i] = *(const bf16x8*)&As[(64 * wr + 16 * i + ln15) * 40 + quad * 8];
#pragma unroll
    for (int j = 0; j < 4; ++j)
      bw[j] = *(const bf16x8*)&Ws[(64 * wc + 16 * j + ln15) * 40 + quad * 8];
#pragma unroll
    for (int i = 0; i < 4; ++i)
#pragma unroll
      for (int j = 0; j < 4; ++j)
        acc[i][j] = __builtin_amdgcn_mfma_f32_16x16x32_bf16(af[i], bw[j], acc[i][j], 0, 0, 0);
    __syncthreads();
  }

#pragma unroll
  for (int i = 0; i < 4; ++i)
#pragma unroll
    for (int j = 0; j < 4; ++j) {
      int col = tn + 64 * wc + 16 * j + ln15;
      float badd = HAS_BIAS ? bias[col] : 0.0f;
#pragma unroll
      for (int r = 0; r < 4; ++r) {
        int row = tm + 64 * wr + 16 * i + 4 * quad + r;
        float val = acc[i][j][r] + badd;
        if (OUT_F32) ((float*)Cv)[(size_t)row * N + col] = val;
        else         ((ushort*)Cv)[(size_t)row * N + col] = f2bf(val);
      }
    }
}

// ---- RoPE in place on q,k of mixed[s][n*384 + {0..127 q, 128..255 k}] (bf16) ------------
__global__ __launch_bounds__(256) void rope_kernel(ushort* __restrict__ mixed) {
  int t = blockIdx.x * 256 + threadIdx.x;   // S*NH*64 threads
  int d = t & 63;
  int n = (t >> 6) & (NHEAD - 1);
  int s = t >> 10;
  ushort* base = mixed + (size_t)s * H3 + n * 384;
  double invf = pow(10000.0, -(double)d / 64.0);
  double ang = (double)s * invf;
  double sd, cd; sincos(ang, &sd, &cd);
  float c = (float)cd, si = (float)sd;
  float q0 = bf2f(base[d]),       q1 = bf2f(base[64 + d]);
  float k0 = bf2f(base[128 + d]), k1 = bf2f(base[192 + d]);
  base[d]       = f2bf(q0 * c - q1 * si);
  base[64 + d]  = f2bf(q1 * c + q0 * si);
  base[128 + d] = f2bf(k0 * c - k1 * si);
  base[192 + d] = f2bf(k1 * c + k0 * si);
}

// ---- V transpose: mixed v-part (bf16) -> vt[n][d][s] (bf16) -----------------------------
__global__ __launch_bounds__(256) void v_transpose(const ushort* __restrict__ mixed,
                                                   ushort* __restrict__ vt) {
  __shared__ __align__(16) ushort Vl[64 * 136];
  const int tid = threadIdx.x;
  const int sb = blockIdx.x;   // 0..31
  const int n  = blockIdx.y;   // 0..15
#pragma unroll
  for (int it = 0; it < 4; ++it) {
    int c = tid + it * 256;
    int row = c >> 4, dp = (c & 15) * 8;
    *(int4*)&Vl[row * 136 + dp] =
        *(const int4*)&mixed[(size_t)(sb * 64 + row) * H3 + n * 384 + 256 + dp];
  }
  __syncthreads();
#pragma unroll
  for (int it = 0; it < 4; ++it) {
    int c = tid + it * 256;
    int d = c >> 3, sp = (c & 7) * 8;
    union { ushort u[8]; int4 v; } pk;
#pragma unroll
    for (int e = 0; e < 8; ++e) pk.u[e] = Vl[(sp + e) * 136 + d];
    *(int4*)&vt[((size_t)(n * 128 + d)) * S_LEN + sb * 64 + sp] = pk.v;
  }
}

// ---- Flash attention: block = (64 q rows, head). Wave w owns strip rows 16w..16w+15.
// Q frags in registers; m/l/alpha register-resident; P round-trips wave-private LDS.
__global__ __launch_bounds__(256) void attn_kernel(const ushort* __restrict__ mixed,
                                                   const ushort* __restrict__ vt,
                                                   ushort* __restrict__ ctx,
                                                   int CS, int CH) {
  __shared__ __align__(16) ushort Ks[64 * 136];
  __shared__ __align__(16) ushort Vt[128 * 72];
  __shared__ __align__(16) float  Ss[4 * 16 * 68];   // per-wave 16x64 P tile

  const int tid  = threadIdx.x;
  const int lane = tid & 63;
  const int w    = tid >> 6;
  const int quad = lane >> 4, ln15 = lane & 15;
  const int qb = blockIdx.x;   // q block 0..31
  const int n  = blockIdx.y;   // head
  const float scale = 0.08838834764831845f;  // 1/sqrt(128)

  bf16x8 aqr[4];   // A-layout Q: row m=ln15 of strip, k = ks*32 + quad*8 + j
#pragma unroll
  for (int ks = 0; ks < 4; ++ks)
    aqr[ks] = *(const bf16x8*)&mixed[(size_t)(qb * 64 + 16 * w + ln15) * H3 + n * 384
                                     + ks * 32 + quad * 8];

  f32x4 acc_o[8];
#pragma unroll
  for (int jt = 0; jt < 8; ++jt) acc_o[jt] = (f32x4){0.f, 0.f, 0.f, 0.f};
  float m_run[4], l_run[4];
#pragma unroll
  for (int r = 0; r < 4; ++r) { m_run[r] = -1e30f; l_run[r] = 0.0f; }

  float* Ssw = &Ss[w * 16 * 68];

  for (int kt = 0; kt <= qb; ++kt) {
#pragma unroll
    for (int it = 0; it < 4; ++it) {
      int c = tid + it * 256;
      int row = c >> 4, dp = (c & 15) * 8;
      *(int4*)&Ks[row * 136 + dp] =
          *(const int4*)&mixed[(size_t)(kt * 64 + row) * H3 + n * 384 + 128 + dp];
      int d = c >> 3, sp = (c & 7) * 8;
      *(int4*)&Vt[d * 72 + sp] =
          *(const int4*)&vt[((size_t)(n * 128 + d)) * S_LEN + kt * 64 + sp];
    }
    __syncthreads();

    f32x4 sacc[4];
#pragma unroll
    for (int jt = 0; jt < 4; ++jt) sacc[jt] = (f32x4){0.f, 0.f, 0.f, 0.f};
#pragma unroll
    for (int ks = 0; ks < 4; ++ks) {
#pragma unroll
      for (int jt = 0; jt < 4; ++jt) {
        bf16x8 bk = *(const bf16x8*)&Ks[(16 * jt + ln15) * 136 + ks * 32 + quad * 8];
        sacc[jt] = __builtin_amdgcn_mfma_f32_16x16x32_bf16(aqr[ks], bk, sacc[jt], 0, 0, 0);
      }
    }

    float sv[4][4];
    const int ig = qb * 64 + 16 * w + 4 * quad;
#pragma unroll
    for (int jt = 0; jt < 4; ++jt) {
      int jg = kt * 64 + 16 * jt + ln15;
#pragma unroll
      for (int r = 0; r < 4; ++r) {
        float x = sacc[jt][r] * scale;
        sv[jt][r] = (jg > ig + r) ? -10000.0f : x;
      }
    }

    float tmx[4];
#pragma unroll
    for (int r = 0; r < 4; ++r)
      tmx[r] = fmaxf(fmaxf(sv[0][r], sv[1][r]), fmaxf(sv[2][r], sv[3][r]));
#pragma unroll
    for (int m = 1; m <= 8; m <<= 1)
#pragma unroll
      for (int r = 0; r < 4; ++r) tmx[r] = fmaxf(tmx[r], __shfl_xor(tmx[r], m));

    float alpha[4];
#pragma unroll
    for (int r = 0; r < 4; ++r) {
      float m_new = fmaxf(m_run[r], tmx[r]);
      alpha[r] = __expf(m_run[r] - m_new);
      m_run[r] = m_new;
    }

    float ps[4] = {0.f, 0.f, 0.f, 0.f};
#pragma unroll
    for (int jt = 0; jt < 4; ++jt)
#pragma unroll
      for (int r = 0; r < 4; ++r) {
        float p = __expf(sv[jt][r] - m_run[r]);
        Ssw[(4 * quad + r) * 68 + 16 * jt + ln15] = p;
        ps[r] += p;
      }
#pragma unroll
    for (int m = 1; m <= 8; m <<= 1)
#pragma unroll
      for (int r = 0; r < 4; ++r) ps[r] += __shfl_xor(ps[r], m);
#pragma unroll
    for (int r = 0; r < 4; ++r) l_run[r] = alpha[r] * l_run[r] + ps[r];

#pragma unroll
    for (int jt = 0; jt < 8; ++jt)
#pragma unroll
      for (int r = 0; r < 4; ++r) acc_o[jt][r] *= alpha[r];
#pragma unroll
    for (int ks = 0; ks < 2; ++ks) {
      const float* pp = &Ssw[ln15 * 68 + ks * 32 + quad * 8];
      float4 p0 = *(const float4*)(pp);
      float4 p1 = *(const float4*)(pp + 4);
      bf16x8 ap;
      ap[0] = (short)f2bf(p0.x); ap[1] = (short)f2bf(p0.y);
      ap[2] = (short)f2bf(p0.z); ap[3] = (short)f2bf(p0.w);
      ap[4] = (short)f2bf(p1.x); ap[5] = (short)f2bf(p1.y);
      ap[6] = (short)f2bf(p1.z); ap[7] = (short)f2bf(p1.w);
#pragma unroll
      for (int jt = 0; jt < 8; ++jt) {
        bf16x8 bv = *(const bf16x8*)&Vt[(16 * jt + ln15) * 72 + ks * 32 + quad * 8];
        acc_o[jt] = __builtin_amdgcn_mfma_f32_16x16x32_bf16(ap, bv, acc_o[jt], 0, 0, 0);
      }
    }
    __syncthreads();
  }

  float rinv[4];
#pragma unroll
  for (int r = 0; r < 4; ++r) rinv[r] = 1.0f / l_run[r];
#pragma unroll
  for (int jt = 0; jt < 8; ++jt)
#pragma unroll
    for (int r = 0; r < 4; ++r) {
      int row = qb * 64 + 16 * w + 4 * quad + r;
      int col = 16 * jt + ln15;
      ctx[(size_t)row * CS + n * CH + col] = f2bf(acc_o[jt][r] * rinv[r]);
    }
}

// ---- launch ------------------------------------------------------------------------------
extern "C" void kernel_launch(void* const* d_in, const int* in_sizes, int n_in,
                              void* d_out, int out_size, void* d_ws, size_t ws_size,
                              hipStream_t stream) {
  const float* hidden  = (const float*)d_in[0];
  // d_in[1] = attention_mask (causal triu) — structure known, not read
  const float* w_qkv   = (const float*)d_in[2];
  const float* b_qkv   = (const float*)d_in[3];
  const float* w_dense = (const float*)d_in[4];
  float* out = (float*)d_out;

  const size_t mixed_b = (size_t)S_LEN * H3 * 2;           // 25,165,824 B
  const size_t vt_b    = (size_t)NHEAD * HDIM * S_LEN * 2; //  8,388,608 B
  const size_t ctx_b   = (size_t)S_LEN * HID * 2;          //  8,388,608 B

  char* ws = (char*)d_ws;
  ushort* mixed = (ushort*)ws;
  ushort* vt    = (ushort*)(ws + mixed_b);

  // ws-adaptive ctx placement (branch depends only on ws_size). Small path: ctx lives in
  // the q-slots of mixed — each attn block is sole reader of its own q rows and loads them
  // into registers before its final write, so the overwrite is race-free.
  const bool big = ws_size >= mixed_b + vt_b + ctx_b;
  ushort* ctx = big ? (ushort*)(ws + mixed_b + vt_b) : mixed;
  const int CS = big ? HID  : H3;    // ctx row stride
  const int CH = big ? HDIM : 384;   // ctx per-head offset

  gemm_bt<true, true, false><<<dim3(48, 16), 256, 0, stream>>>(
      hidden, w_qkv, b_qkv, mixed, S_LEN, H3, HID, HID, HDIM);
  rope_kernel<<<8192, 256, 0, stream>>>(mixed);
  v_transpose<<<dim3(32, 16), 256, 0, stream>>>(mixed, vt);
  attn_kernel<<<dim3(32, 16), 256, 0, stream>>>(mixed, vt, ctx, CS, CH);
  gemm_bt<false, false, true><<<dim3(16, 16), 256, 0, stream>>>(
      ctx, w_dense, nullptr, out, S_LEN, HID, HID, CS, CH);
}

// Round 5
// 353.184 us; speedup vs baseline: 1.1549x; 1.1549x over previous
//
#include <hip/hip_runtime.h>

// ParallelSelfAttention: S=2048 B=1 H=2048 NH=16 HD=128. I/O f32, internal bf16 MFMA.
// Fast path (ws>=64MiB): pre-convert inputs to bf16, GEMMs stage via global_load_lds(16B).
// Fallback: round-4 proven path (cvt-in-staging GEMM).

#define S_LEN 2048
#define NHEAD 16
#define HDIM  128
#define HID   2048
#define H3    6144

typedef short bf16x8 __attribute__((ext_vector_type(8)));
typedef float f32x4  __attribute__((ext_vector_type(4)));

__device__ __forceinline__ float bf2f(ushort u) {
  union { float f; unsigned int i; } v; v.i = ((unsigned int)u) << 16; return v.f;
}
__device__ __forceinline__ ushort f2bf(float f) {
  union { float f; unsigned int i; } v; v.f = f;
  unsigned int r = v.i + 0x7fffu + ((v.i >> 16) & 1u);
  return (ushort)(r >> 16);
}
__device__ __forceinline__ int4 cvt8(const float* p) {
  float4 a = *(const float4*)p, b = *(const float4*)(p + 4);
  union { ushort u[8]; int4 v; } r;
  r.u[0] = f2bf(a.x); r.u[1] = f2bf(a.y); r.u[2] = f2bf(a.z); r.u[3] = f2bf(a.w);
  r.u[4] = f2bf(b.x); r.u[5] = f2bf(b.y); r.u[6] = f2bf(b.z); r.u[7] = f2bf(b.w);
  return r.v;
}

// async global->LDS DMA, 16B per lane; LDS dest = wave-uniform base + lane*16
typedef __attribute__((address_space(1))) const unsigned int gu32;
typedef __attribute__((address_space(3))) unsigned int lu32;
__device__ __forceinline__ void async16(const void* g, void* l) {
  __builtin_amdgcn_global_load_lds((gu32*)g, (lu32*)l, 16, 0, 0);
}

// ---- f32 -> bf16 elementwise convert (8 elems/thread) -----------------------------------
__global__ __launch_bounds__(256) void cvt_bf16(const float* __restrict__ src,
                                                ushort* __restrict__ dst, int n8) {
  int i = blockIdx.x * 256 + threadIdx.x;
  if (i < n8) *(int4*)&dst[(size_t)i * 8] = cvt8(&src[(size_t)i * 8]);
}

// ---- Fast GEMM: C[M,N] = A @ W^T (+bias). A,W bf16; staging via global_load_lds. --------
// A element (row,k) at A[row*AS + (k>>7)*AH + (k&127)]. Block tile BM x BN, BK=32,
// 4 waves in 2x2, wave tile (BM/2)x(BN/2).
template<int BM, int BN, bool HAS_BIAS, bool OUT_F32>
__global__ __launch_bounds__(256) void gemm_async(const ushort* __restrict__ A,
                                                  const ushort* __restrict__ W,
                                                  const float* __restrict__ bias,
                                                  void* __restrict__ Cv,
                                                  int N, int K, int AS, int AH) {
  __shared__ __align__(16) ushort As[BM * 32];
  __shared__ __align__(16) ushort Ws[BN * 32];
  const int tid  = threadIdx.x;
  const int lane = tid & 63;
  const int w    = tid >> 6;
  const int wr   = w >> 1, wc = w & 1;
  const int quad = lane >> 4, ln15 = lane & 15;
  const int tm = blockIdx.y * BM, tn = blockIdx.x * BN;
  constexpr int MI = BM / 32, NJ = BN / 32;

  f32x4 acc[MI][NJ];
#pragma unroll
  for (int i = 0; i < MI; ++i)
#pragma unroll
    for (int j = 0; j < NJ; ++j) acc[i][j] = (f32x4){0.f, 0.f, 0.f, 0.f};

  const int lrow = lane >> 2;          // 0..15 within a 16-row issue
  const int lcol = (lane & 3) * 8;     // k element offset within 32-chunk

  for (int k0 = 0; k0 < K; k0 += 32) {
    const int aoff = (k0 >> 7) * AH + (k0 & 127) + lcol;
    for (int r = w; r < (BM + BN) / 16; r += 4) {
      if (r < BM / 16) {
        async16(&A[(size_t)(tm + r * 16 + lrow) * AS + aoff], &As[r * 16 * 32]);
      } else {
        const int rb = r - BM / 16;
        async16(&W[(size_t)(tn + rb * 16 + lrow) * K + k0 + lcol], &Ws[rb * 16 * 32]);
      }
    }
    __syncthreads();
    bf16x8 af[MI], bw[NJ];
#pragma unroll
    for (int i = 0; i < MI; ++i)
      af[i] = *(const bf16x8*)&As[((BM / 2) * wr + 16 * i + ln15) * 32 + quad * 8];
#pragma unroll
    for (int j = 0; j < NJ; ++j)
      bw[j] = *(const bf16x8*)&Ws[((BN / 2) * wc + 16 * j + ln15) * 32 + quad * 8];
#pragma unroll
    for (int i = 0; i < MI; ++i)
#pragma unroll
      for (int j = 0; j < NJ; ++j)
        acc[i][j] = __builtin_amdgcn_mfma_f32_16x16x32_bf16(af[i], bw[j], acc[i][j], 0, 0, 0);
    __syncthreads();
  }

#pragma unroll
  for (int i = 0; i < MI; ++i)
#pragma unroll
    for (int j = 0; j < NJ; ++j) {
      int col = tn + (BN / 2) * wc + 16 * j + ln15;
      float badd = HAS_BIAS ? bias[col] : 0.0f;
#pragma unroll
      for (int r = 0; r < 4; ++r) {
        int row = tm + (BM / 2) * wr + 16 * i + 4 * quad + r;
        float val = acc[i][j][r] + badd;
        if (OUT_F32) ((float*)Cv)[(size_t)row * N + col] = val;
        else         ((ushort*)Cv)[(size_t)row * N + col] = f2bf(val);
      }
    }
}

// ---- Fallback GEMM (round-4 proven): A f32-or-bf16, W f32, cvt in staging ---------------
template<bool A_F32, bool HAS_BIAS, bool OUT_F32>
__global__ __launch_bounds__(256) void gemm_bt(const void* __restrict__ Av,
                                               const float* __restrict__ W,
                                               const float* __restrict__ bias,
                                               void* __restrict__ Cv,
                                               int M, int N, int K, int AS, int AH) {
  __shared__ __align__(16) ushort As[128 * 40];
  __shared__ __align__(16) ushort Ws[128 * 40];
  const int tid  = threadIdx.x;
  const int lane = tid & 63;
  const int w    = tid >> 6;
  const int wr   = w >> 1, wc = w & 1;
  const int quad = lane >> 4, ln15 = lane & 15;
  const int tm = blockIdx.y * 128, tn = blockIdx.x * 128;

  f32x4 acc[4][4];
#pragma unroll
  for (int i = 0; i < 4; ++i)
#pragma unroll
    for (int j = 0; j < 4; ++j) acc[i][j] = (f32x4){0.f, 0.f, 0.f, 0.f};

  const int row0 = tid >> 2, row1 = row0 + 64;
  const int kp   = (tid & 3) * 8;

  for (int k0 = 0; k0 < K; k0 += 32) {
    const int ka   = k0 + kp;
    const int aoff = (ka >> 7) * AH + (ka & 127);
    if (A_F32) {
      const float* A = (const float*)Av;
      *(int4*)&As[row0 * 40 + kp] = cvt8(&A[(size_t)(tm + row0) * AS + aoff]);
      *(int4*)&As[row1 * 40 + kp] = cvt8(&A[(size_t)(tm + row1) * AS + aoff]);
    } else {
      const ushort* A = (const ushort*)Av;
      *(int4*)&As[row0 * 40 + kp] = *(const int4*)&A[(size_t)(tm + row0) * AS + aoff];
      *(int4*)&As[row1 * 40 + kp] = *(const int4*)&A[(size_t)(tm + row1) * AS + aoff];
    }
    *(int4*)&Ws[row0 * 40 + kp] = cvt8(&W[(size_t)(tn + row0) * K + ka]);
    *(int4*)&Ws[row1 * 40 + kp] = cvt8(&W[(size_t)(tn + row1) * K + ka]);
    __syncthreads();
    bf16x8 af[4], bw[4];
#pragma unroll
    for (int i = 0; i < 4; ++i)
      af[i] = *(const bf16x8*)&As[(64 * wr + 16 * i + ln15) * 40 + quad * 8];
#pragma unroll
    for (int j = 0; j < 4; ++j)
      bw[j] = *(const bf16x8*)&Ws[(64 * wc + 16 * j + ln15) * 40 + quad * 8];
#pragma unroll
    for (int i = 0; i < 4; ++i)
#pragma unroll
      for (int j = 0; j < 4; ++j)
        acc[i][j] = __builtin_amdgcn_mfma_f32_16x16x32_bf16(af[i], bw[j], acc[i][j], 0, 0, 0);
    __syncthreads();
  }

#pragma unroll
  for (int i = 0; i < 4; ++i)
#pragma unroll
    for (int j = 0; j < 4; ++j) {
      int col = tn + 64 * wc + 16 * j + ln15;
      float badd = HAS_BIAS ? bias[col] : 0.0f;
#pragma unroll
      for (int r = 0; r < 4; ++r) {
        int row = tm + 64 * wr + 16 * i + 4 * quad + r;
        float val = acc[i][j][r] + badd;
        if (OUT_F32) ((float*)Cv)[(size_t)row * N + col] = val;
        else         ((ushort*)Cv)[(size_t)row * N + col] = f2bf(val);
      }
    }
}

// ---- RoPE in place on q,k of mixed[s][n*384 + {q,k,v}] (bf16), float sincos -------------
__global__ __launch_bounds__(256) void rope_kernel(ushort* __restrict__ mixed) {
  int t = blockIdx.x * 256 + threadIdx.x;   // S*NH*64 threads
  int d = t & 63;
  int n = (t >> 6) & (NHEAD - 1);
  int s = t >> 10;
  ushort* base = mixed + (size_t)s * H3 + n * 384;
  // inv_freq = 10000^(-d/64); log2(10000) = 13.287712379549449
  float invf = exp2f((float)d * (-13.287712379549449f / 64.0f));
  float ang = (float)s * invf;
  float si, c; sincosf(ang, &si, &c);
  float q0 = bf2f(base[d]),       q1 = bf2f(base[64 + d]);
  float k0 = bf2f(base[128 + d]), k1 = bf2f(base[192 + d]);
  base[d]       = f2bf(q0 * c - q1 * si);
  base[64 + d]  = f2bf(q1 * c + q0 * si);
  base[128 + d] = f2bf(k0 * c - k1 * si);
  base[192 + d] = f2bf(k1 * c + k0 * si);
}

// ---- V transpose: mixed v-part (bf16) -> vt[n][d][s] ------------------------------------
__global__ __launch_bounds__(256) void v_transpose(const ushort* __restrict__ mixed,
                                                   ushort* __restrict__ vt) {
  __shared__ __align__(16) ushort Vl[64 * 136];
  const int tid = threadIdx.x;
  const int sb = blockIdx.x;
  const int n  = blockIdx.y;
#pragma unroll
  for (int it = 0; it < 4; ++it) {
    int c = tid + it * 256;
    int row = c >> 4, dp = (c & 15) * 8;
    *(int4*)&Vl[row * 136 + dp] =
        *(const int4*)&mixed[(size_t)(sb * 64 + row) * H3 + n * 384 + 256 + dp];
  }
  __syncthreads();
#pragma unroll
  for (int it = 0; it < 4; ++it) {
    int c = tid + it * 256;
    int d = c >> 3, sp = (c & 7) * 8;
    union { ushort u[8]; int4 v; } pk;
#pragma unroll
    for (int e = 0; e < 8; ++e) pk.u[e] = Vl[(sp + e) * 136 + d];
    *(int4*)&vt[((size_t)(n * 128 + d)) * S_LEN + sb * 64 + sp] = pk.v;
  }
}

// ---- Flash attention (validated round 4) ------------------------------------------------
__global__ __launch_bounds__(256) void attn_kernel(const ushort* __restrict__ mixed,
                                                   const ushort* __restrict__ vt,
                                                   ushort* __restrict__ ctx,
                                                   int CS, int CH) {
  __shared__ __align__(16) ushort Ks[64 * 136];
  __shared__ __align__(16) ushort Vt[128 * 72];
  __shared__ __align__(16) float  Ss[4 * 16 * 68];

  const int tid  = threadIdx.x;
  const int lane = tid & 63;
  const int w    = tid >> 6;
  const int quad = lane >> 4, ln15 = lane & 15;
  const int qb = blockIdx.x;
  const int n  = blockIdx.y;
  const float scale = 0.08838834764831845f;

  bf16x8 aqr[4];
#pragma unroll
  for (int ks = 0; ks < 4; ++ks)
    aqr[ks] = *(const bf16x8*)&mixed[(size_t)(qb * 64 + 16 * w + ln15) * H3 + n * 384
                                     + ks * 32 + quad * 8];

  f32x4 acc_o[8];
#pragma unroll
  for (int jt = 0; jt < 8; ++jt) acc_o[jt] = (f32x4){0.f, 0.f, 0.f, 0.f};
  float m_run[4], l_run[4];
#pragma unroll
  for (int r = 0; r < 4; ++r) { m_run[r] = -1e30f; l_run[r] = 0.0f; }

  float* Ssw = &Ss[w * 16 * 68];

  for (int kt = 0; kt <= qb; ++kt) {
#pragma unroll
    for (int it = 0; it < 4; ++it) {
      int c = tid + it * 256;
      int row = c >> 4, dp = (c & 15) * 8;
      *(int4*)&Ks[row * 136 + dp] =
          *(const int4*)&mixed[(size_t)(kt * 64 + row) * H3 + n * 384 + 128 + dp];
      int d = c >> 3, sp = (c & 7) * 8;
      *(int4*)&Vt[d * 72 + sp] =
          *(const int4*)&vt[((size_t)(n * 128 + d)) * S_LEN + kt * 64 + sp];
    }
    __syncthreads();

    f32x4 sacc[4];
#pragma unroll
    for (int jt = 0; jt < 4; ++jt) sacc[jt] = (f32x4){0.f, 0.f, 0.f, 0.f};
#pragma unroll
    for (int ks = 0; ks < 4; ++ks) {
#pragma unroll
      for (int jt = 0; jt < 4; ++jt) {
        bf16x8 bk = *(const bf16x8*)&Ks[(16 * jt + ln15) * 136 + ks * 32 + quad * 8];
        sacc[jt] = __builtin_amdgcn_mfma_f32_16x16x32_bf16(aqr[ks], bk, sacc[jt], 0, 0, 0);
      }
    }

    float sv[4][4];
    const int ig = qb * 64 + 16 * w + 4 * quad;
#pragma unroll
    for (int jt = 0; jt < 4; ++jt) {
      int jg = kt * 64 + 16 * jt + ln15;
#pragma unroll
      for (int r = 0; r < 4; ++r) {
        float x = sacc[jt][r] * scale;
        sv[jt][r] = (jg > ig + r) ? -10000.0f : x;
      }
    }

    float tmx[4];
#pragma unroll
    for (int r = 0; r < 4; ++r)
      tmx[r] = fmaxf(fmaxf(sv[0][r], sv[1][r]), fmaxf(sv[2][r], sv[3][r]));
#pragma unroll
    for (int m = 1; m <= 8; m <<= 1)
#pragma unroll
      for (int r = 0; r < 4; ++r) tmx[r] = fmaxf(tmx[r], __shfl_xor(tmx[r], m));

    float alpha[4];
#pragma unroll
    for (int r = 0; r < 4; ++r) {
      float m_new = fmaxf(m_run[r], tmx[r]);
      alpha[r] = __expf(m_run[r] - m_new);
      m_run[r] = m_new;
    }

    float ps[4] = {0.f, 0.f, 0.f, 0.f};
#pragma unroll
    for (int jt = 0; jt < 4; ++jt)
#pragma unroll
      for (int r = 0; r < 4; ++r) {
        float p = __expf(sv[jt][r] - m_run[r]);
        Ssw[(4 * quad + r) * 68 + 16 * jt + ln15] = p;
        ps[r] += p;
      }
#pragma unroll
    for (int m = 1; m <= 8; m <<= 1)
#pragma unroll
      for (int r = 0; r < 4; ++r) ps[r] += __shfl_xor(ps[r], m);
#pragma unroll
    for (int r = 0; r < 4; ++r) l_run[r] = alpha[r] * l_run[r] + ps[r];

#pragma unroll
    for (int jt = 0; jt < 8; ++jt)
#pragma unroll
      for (int r = 0; r < 4; ++r) acc_o[jt][r] *= alpha[r];
#pragma unroll
    for (int ks = 0; ks < 2; ++ks) {
      const float* pp = &Ssw[ln15 * 68 + ks * 32 + quad * 8];
      float4 p0 = *(const float4*)(pp);
      float4 p1 = *(const float4*)(pp + 4);
      bf16x8 ap;
      ap[0] = (short)f2bf(p0.x); ap[1] = (short)f2bf(p0.y);
      ap[2] = (short)f2bf(p0.z); ap[3] = (short)f2bf(p0.w);
      ap[4] = (short)f2bf(p1.x); ap[5] = (short)f2bf(p1.y);
      ap[6] = (short)f2bf(p1.z); ap[7] = (short)f2bf(p1.w);
#pragma unroll
      for (int jt = 0; jt < 8; ++jt) {
        bf16x8 bv = *(const bf16x8*)&Vt[(16 * jt + ln15) * 72 + ks * 32 + quad * 8];
        acc_o[jt] = __builtin_amdgcn_mfma_f32_16x16x32_bf16(ap, bv, acc_o[jt], 0, 0, 0);
      }
    }
    __syncthreads();
  }

  float rinv[4];
#pragma unroll
  for (int r = 0; r < 4; ++r) rinv[r] = 1.0f / l_run[r];
#pragma unroll
  for (int jt = 0; jt < 8; ++jt)
#pragma unroll
    for (int r = 0; r < 4; ++r) {
      int row = qb * 64 + 16 * w + 4 * quad + r;
      int col = 16 * jt + ln15;
      ctx[(size_t)row * CS + n * CH + col] = f2bf(acc_o[jt][r] * rinv[r]);
    }
}

// ---- launch ------------------------------------------------------------------------------
extern "C" void kernel_launch(void* const* d_in, const int* in_sizes, int n_in,
                              void* d_out, int out_size, void* d_ws, size_t ws_size,
                              hipStream_t stream) {
  const float* hidden  = (const float*)d_in[0];
  const float* w_qkv   = (const float*)d_in[2];
  const float* b_qkv   = (const float*)d_in[3];
  const float* w_dense = (const float*)d_in[4];
  float* out = (float*)d_out;

  char* ws = (char*)d_ws;

  const size_t wq_b    = (size_t)H3 * HID * 2;             // 25,165,824
  const size_t h_b     = (size_t)S_LEN * HID * 2;          //  8,388,608
  const size_t mixed_b = (size_t)S_LEN * H3 * 2;           // 25,165,824
  const size_t vt_b    = (size_t)NHEAD * HDIM * S_LEN * 2; //  8,388,608
  const size_t fast_need = wq_b + h_b + mixed_b + vt_b;    // 67,108,864 (64 MiB)

  if (ws_size >= fast_need) {
    // fast path: bf16 pre-convert + async-staged GEMMs
    ushort* WQ    = (ushort*)ws;                       // w_qkv bf16 (WD reuses this later)
    ushort* Hbf   = (ushort*)(ws + wq_b);
    ushort* mixed = (ushort*)(ws + wq_b + h_b);
    ushort* vt    = (ushort*)(ws + wq_b + h_b + mixed_b);
    ushort* WD    = WQ;                                // w_qkv dead after QKV GEMM
    ushort* ctx   = mixed;                             // q-slots of mixed (race-free)

    cvt_bf16<<<2048, 256, 0, stream>>>(hidden, Hbf, S_LEN * HID / 8);
    cvt_bf16<<<6144, 256, 0, stream>>>(w_qkv, WQ, H3 * HID / 8);
    gemm_async<128, 128, true, false><<<dim3(48, 16), 256, 0, stream>>>(
        Hbf, WQ, b_qkv, mixed, H3, HID, HID, 128);
    rope_kernel<<<8192, 256, 0, stream>>>(mixed);
    v_transpose<<<dim3(32, 16), 256, 0, stream>>>(mixed, vt);
    attn_kernel<<<dim3(32, 16), 256, 0, stream>>>(mixed, vt, ctx, H3, 384);
    cvt_bf16<<<2048, 256, 0, stream>>>(w_dense, WD, HID * HID / 8);
    gemm_async<64, 128, false, true><<<dim3(16, 32), 256, 0, stream>>>(
        ctx, WD, nullptr, out, HID, HID, H3, 384);
  } else {
    // fallback: round-4 proven path
    ushort* mixed = (ushort*)ws;
    ushort* vt    = (ushort*)(ws + mixed_b);
    const bool big = ws_size >= mixed_b + vt_b + (size_t)S_LEN * HID * 2;
    ushort* ctx = big ? (ushort*)(ws + mixed_b + vt_b) : mixed;
    const int CS = big ? HID  : H3;
    const int CH = big ? HDIM : 384;

    gemm_bt<true, true, false><<<dim3(48, 16), 256, 0, stream>>>(
        hidden, w_qkv, b_qkv, mixed, S_LEN, H3, HID, HID, HDIM);
    rope_kernel<<<8192, 256, 0, stream>>>(mixed);
    v_transpose<<<dim3(32, 16), 256, 0, stream>>>(mixed, vt);
    attn_kernel<<<dim3(32, 16), 256, 0, stream>>>(mixed, vt, ctx, CS, CH);
    gemm_bt<false, false, true><<<dim3(16, 16), 256, 0, stream>>>(
        ctx, w_dense, nullptr, out, S_LEN, HID, HID, CS, CH);
  }
}